// Round 11
// baseline (532.577 us; speedup 1.0000x reference)
//
#include <hip/hip_runtime.h>
#include <hip/hip_bf16.h>
#include <stdint.h>

// ---------------- problem dims ----------------
#define BTOT   65536
#define DIN    784
#define NH1    256
#define NH2    64
#define NEXP   10
#define BM     256
#define NKS1   25      // K1 = 800 (784 + bias row @784 + zeros), 25 steps of 32

// ---------------- LDS layout (bytes) ----------------
// stage: 2 bufs x {x-slice 16K (8mb x 2kh x 1024) | W-slice 16K (8nb x 2kh x 1024)}
#define XBUF(b)   (lds + (b) * 32768)
#define WBUF(b)   (lds + (b) * 32768 + 16384)
#define H_OFF     65536                    // h-half: [mtile8][ks2l4][kh2][lane64][8] = 64K
#define EXPL_OFF  131072                   // [256 m][10 e] f32 = 10240
#define B2S_OFF   141312                   // [10][64] f32 = 2560
#define W3S_OFF   143872                   // [10][64] f32 = 2560
#define B3S_OFF   146432                   // 64
#define BG2S_OFF  146496                   // 64
#define LDS_TOTAL 146560

typedef short s16x8  __attribute__((ext_vector_type(8)));
typedef float f32x4  __attribute__((ext_vector_type(4)));
typedef float f32x16 __attribute__((ext_vector_type(16)));

__device__ __forceinline__ short bf16b(float v) {
    __bf16 b = (__bf16)v;
    return __builtin_bit_cast(short, b);
}

__device__ __forceinline__ void g2l16(const void* g, void* l) {
    __builtin_amdgcn_global_load_lds(
        (const __attribute__((address_space(1))) unsigned char*)g,
        (__attribute__((address_space(3))) unsigned char*)l, 16, 0, 0);
}

// ---------------- prep: fragment-order weights (bf16, b1 folded) ------------
// w1t [e11][ks25][nb8][kh2][lane64][8]: n=nb*32+(lane&31),
// k=ks*32+kh*16+(lane>>5)*8+j; k==784 -> bias; e==10 -> gate Wg1/bg1.
__global__ void prep_w1(const float* __restrict__ W1, const float* __restrict__ b1,
                        const float* __restrict__ Wg1, const float* __restrict__ bg1,
                        __bf16* __restrict__ dst) {
    int t = blockIdx.x * 256 + threadIdx.x;          // < 281600
    int lane = t & 63;
    int kh = (t >> 6) & 1;
    int nb = (t >> 7) & 7;
    int r  = t >> 10;
    int ks = r % 25, e = r / 25;
    int n  = nb * 32 + (lane & 31);
    int k0 = ks * 32 + kh * 16 + (lane >> 5) * 8;
    const float* src  = (e < NEXP) ? (W1 + (size_t)e * DIN * NH1) : Wg1;
    const float* bias = (e < NEXP) ? (b1 + e * NH1) : bg1;
    s16x8 o;
    #pragma unroll
    for (int j = 0; j < 8; ++j) {
        int k = k0 + j;
        float v = (k < DIN) ? src[(size_t)k * NH1 + n]
                            : ((k == DIN) ? bias[n] : 0.f);
        o[j] = bf16b(v);
    }
    *(s16x8*)((short*)dst + (size_t)t * 8) = o;
}

// w2t [e10][jb2][ks8][kh2][lane64][8]: n=jb*32+(lane&31), k fragment coords (K2=256).
__global__ void prep_w2(const float* __restrict__ W2, __bf16* __restrict__ dst) {
    int t = blockIdx.x * 256 + threadIdx.x;          // < 20480
    int lane = t & 63;
    int kh = (t >> 6) & 1;
    int ks = (t >> 7) & 7;
    int jb = (t >> 10) & 1;
    int e  = t >> 11;
    int n  = jb * 32 + (lane & 31);
    int k0 = ks * 32 + kh * 16 + (lane >> 5) * 8;
    s16x8 o;
    #pragma unroll
    for (int j = 0; j < 8; ++j)
        o[j] = bf16b(W2[((size_t)e * NH1 + k0 + j) * NH2 + n]);
    *(s16x8*)((short*)dst + (size_t)t * 8) = o;
}

// wg2t [ks8][kh2][lane64][8]: col = lane&31 (valid <10), K2=256.
__global__ void prep_wg2(const float* __restrict__ Wg2, __bf16* __restrict__ dst) {
    int t = blockIdx.x * 256 + threadIdx.x;
    if (t >= 1024) return;
    int lane = t & 63;
    int kh = (t >> 6) & 1;
    int ks = t >> 7;
    int n  = lane & 31;
    int k0 = ks * 32 + kh * 16 + (lane >> 5) * 8;
    s16x8 o;
    #pragma unroll
    for (int j = 0; j < 8; ++j)
        o[j] = bf16b((n < NEXP) ? Wg2[(size_t)(k0 + j) * NEXP + n] : 0.f);
    *(s16x8*)((short*)dst + (size_t)t * 8) = o;
}

// ---------------- fused MoE kernel ----------------
// grid 256 blocks x 512 thr (8 waves, 2/SIMD). Block owns 256 rows.
// Per expert: 256x256 layer-1 GEMM, K-step 32, LDS double-buffered:
// W1 via global_load_lds width-16, x reg-staged fp32->bf16. Per wave: 64m x
// 128n = acc[4][2] f32x16 (128 VGPR). h consumed in 128-col halves through a
// 64 KB LDS buffer (write-half -> layer-2 partial -> other half). Operand-
// swapped mfma(W, x): D[n][m], m = lane&31, n = (r&3)+8*(r>>2)+4*(lane>>5).
__global__ void __launch_bounds__(512, 2)
moe_fused(const float* __restrict__ x, const float* __restrict__ b2g,
          const float* __restrict__ W3, const float* __restrict__ b3,
          const float* __restrict__ bg2, const __bf16* __restrict__ w1t,
          const __bf16* __restrict__ w2t, const __bf16* __restrict__ wg2t,
          float* __restrict__ out)
{
    extern __shared__ char lds[];
    char*  hb   = lds + H_OFF;
    float* expl = (float*)(lds + EXPL_OFF);
    float* b2s  = (float*)(lds + B2S_OFF);
    float* w3s  = (float*)(lds + W3S_OFF);
    float* b3s  = (float*)(lds + B3S_OFF);
    float* bg2s = (float*)(lds + BG2S_OFF);

    const int tid  = threadIdx.x;
    const int lane = tid & 63;
    const int wave = tid >> 6;             // 0..7
    const int rl   = lane & 31;
    const int hi   = lane >> 5;
    const int mw   = wave >> 1;            // 0..3 (64-row slice)
    const int nw   = wave & 1;             // 0..1 (128-col half)
    const int row0 = blockIdx.x * BM;
    const char* w1c = (const char*)w1t;
    const char* w2c = (const char*)w2t;
    const char* wgc = (const char*)wg2t;

    // ---- tables ----
    for (int i = tid; i < NEXP * NH2; i += 512) { b2s[i] = b2g[i]; w3s[i] = W3[i]; }
    if (tid < NEXP) { b3s[tid] = b3[tid]; bg2s[tid] = bg2[tid]; }

    // ---- x staging: thread -> (row, k-half); 16 fp32 -> 2 b128 bf16 frags ----
    const int xrow = tid >> 1, xkh = tid & 1;
    const float* xrp = x + (size_t)(row0 + xrow) * DIN + xkh * 16;
    const int xoff = ((xrow >> 5) * 2 + xkh) * 1024 + (xrow & 31) * 16;
    float xf[16];

    #define XLOAD(KS) { if ((KS) < 24 || xkh == 0) {                          \
            _Pragma("unroll") for (int i4 = 0; i4 < 4; ++i4)                  \
                *(float4*)(xf + 4 * i4) =                                     \
                    *(const float4*)(xrp + (KS) * 32 + 4 * i4);               \
        } else { _Pragma("unroll") for (int i4 = 0; i4 < 16; ++i4)            \
                     xf[i4] = 0.f;                                            \
                 xf[0] = 1.f; } }                    /* k=784 bias column */

    #define XWRITE(B) { s16x8 l8, h8;                                         \
            _Pragma("unroll") for (int j = 0; j < 8; ++j) {                   \
                l8[j] = bf16b(xf[j]); h8[j] = bf16b(xf[8 + j]); }             \
            *(s16x8*)(XBUF(B) + xoff)       = l8;                             \
            *(s16x8*)(XBUF(B) + xoff + 512) = h8; }

    #define WSTAGE(B, E, KS) {                                                \
            const char* ws_ = w1c + (((size_t)(E) * 25 + (KS)) << 14)         \
                              + tid * 16;                                     \
            char* wd_ = WBUF(B) + tid * 16;                                   \
            g2l16(ws_, wd_); g2l16(ws_ + 8192, wd_ + 8192); }

    f32x16 acc[4][2];                      // [nt][mt]
    f32x16 acc2[2];                        // layer-2 per jb (gate uses [0])

    #pragma unroll 1
    for (int e = 0; e <= NEXP; ++e) {
        // ---- stage ks=0 into buf0 ----
        XLOAD(0)
        WSTAGE(0, e, 0)
        XWRITE(0)
        __syncthreads();

        #pragma unroll
        for (int nt = 0; nt < 4; ++nt)
            #pragma unroll
            for (int mt = 0; mt < 2; ++mt)
                #pragma unroll
                for (int q = 0; q < 16; ++q) acc[nt][mt][q] = 0.f;
        #pragma unroll
        for (int q = 0; q < 16; ++q) { acc2[0][q] = 0.f; acc2[1][q] = 0.f; }

        // ---- K loop: dbuf, stage(next) issued before compute(cur) ----
        int cur = 0;
        #pragma unroll 1
        for (int ks = 0; ks < NKS1; ++ks) {
            if (ks < 24) {
                XLOAD(ks + 1)              // x loads first (vmcnt-countable)
                WSTAGE(cur ^ 1, e, ks + 1)
            }
            const char* ab = XBUF(cur) + mw * 4096 + lane * 16;
            const char* wb = WBUF(cur) + nw * 8192 + lane * 16;
            s16x8 xv[2][2], wv[4][2];
            #pragma unroll
            for (int mt = 0; mt < 2; ++mt)
                #pragma unroll
                for (int kh = 0; kh < 2; ++kh)
                    xv[mt][kh] = *(const s16x8*)(ab + (mt * 2 + kh) * 1024);
            #pragma unroll
            for (int nt = 0; nt < 4; ++nt)
                #pragma unroll
                for (int kh = 0; kh < 2; ++kh)
                    wv[nt][kh] = *(const s16x8*)(wb + (nt * 2 + kh) * 1024);
            #pragma unroll
            for (int kh = 0; kh < 2; ++kh)
                #pragma unroll
                for (int nt = 0; nt < 4; ++nt)
                    #pragma unroll
                    for (int mt = 0; mt < 2; ++mt)
                        acc[nt][mt] = __builtin_amdgcn_mfma_f32_32x32x16_bf16(
                            wv[nt][kh], xv[mt][kh], acc[nt][mt], 0, 0, 0);
            if (ks < 24) XWRITE(cur ^ 1)   // waits x loads (vmcnt), not W stage
            __syncthreads();               // drains W global_load_lds (covered by MFMA)
            cur ^= 1;
        }

        // ---- epilogue: h in two 128-col halves through 64 KB LDS ----
        #pragma unroll
        for (int half = 0; half < 2; ++half) {
            if (nw == half) {
                // write my acc (n-span = half*128..+128): h[mtile][ks2l=nt][kh][lane][8]
                #pragma unroll
                for (int mt = 0; mt < 2; ++mt)
                    #pragma unroll
                    for (int nt = 0; nt < 4; ++nt)
                        #pragma unroll
                        for (int q = 0; q < 4; ++q) {
                            uint2 wvv; short* p = (short*)&wvv;
                            #pragma unroll
                            for (int r2 = 0; r2 < 4; ++r2)
                                p[r2] = bf16b(fmaxf(acc[nt][mt][q * 4 + r2], 0.f));
                            *(uint2*)(hb + (((mw * 2 + mt) * 4 + nt) * 2 + (q >> 1)) * 1024
                                         + (rl + 32 * (q & 1)) * 16 + hi * 8) = wvv;
                        }
            }
            __syncthreads();               // h-half ready
            if (e < NEXP) {
                #pragma unroll
                for (int jb = 0; jb < 2; ++jb)
                    #pragma unroll
                    for (int k2 = 0; k2 < 4; ++k2)
                        #pragma unroll
                        for (int kh = 0; kh < 2; ++kh) {
                            s16x8 hf = *(const s16x8*)(hb + ((wave * 4 + k2) * 2 + kh) * 1024
                                                       + lane * 16);
                            s16x8 wf = *(const s16x8*)(w2c
                                + ((((size_t)e * 2 + jb) * 8 + half * 4 + k2) * 2 + kh) * 1024
                                + lane * 16);
                            acc2[jb] = __builtin_amdgcn_mfma_f32_32x32x16_bf16(
                                wf, hf, acc2[jb], 0, 0, 0);
                        }
            } else {
                #pragma unroll
                for (int k2 = 0; k2 < 4; ++k2)
                    #pragma unroll
                    for (int kh = 0; kh < 2; ++kh) {
                        s16x8 hf = *(const s16x8*)(hb + ((wave * 4 + k2) * 2 + kh) * 1024
                                                   + lane * 16);
                        s16x8 gf = *(const s16x8*)(wgc
                            + ((half * 4 + k2) * 2 + kh) * 1024 + lane * 16);
                        acc2[0] = __builtin_amdgcn_mfma_f32_32x32x16_bf16(
                            gf, hf, acc2[0], 0, 0, 0);
                    }
            }
            __syncthreads();               // reads done before next half overwrites
        }

        if (e < NEXP) {
            // ---- layer 3: wave owns m-tile = wave; lane m = wave*32+rl ----
            float part = 0.f;
            #pragma unroll
            for (int jb = 0; jb < 2; ++jb)
                #pragma unroll
                for (int q = 0; q < 4; ++q) {
                    f32x4 b2v = *(const f32x4*)(b2s + e * NH2 + jb * 32 + 8 * q + 4 * hi);
                    f32x4 w3v = *(const f32x4*)(w3s + e * NH2 + jb * 32 + 8 * q + 4 * hi);
                    #pragma unroll
                    for (int r2 = 0; r2 < 4; ++r2)
                        part += fmaxf(acc2[jb][q * 4 + r2] + b2v[r2], 0.f) * w3v[r2];
                }
            part += __shfl_xor(part, 32, 64);
            if (hi == 0)
                expl[(wave * 32 + rl) * NEXP + e] = part + b3s[e];
        } else {
            // ---- gate softmax + combine: lane m = wave*32+rl, j = r2+8q+4hi ----
            const int m = wave * 32 + rl;
            float lv[16], mx = -1e30f;
            #pragma unroll
            for (int q = 0; q < 4; ++q)
                #pragma unroll
                for (int r2 = 0; r2 < 4; ++r2) {
                    int j = r2 + 8 * q + 4 * hi;
                    int rg = q * 4 + r2;
                    lv[rg] = (j < NEXP) ? (acc2[0][rg] + bg2s[j]) : -1e30f;
                    mx = fmaxf(mx, lv[rg]);
                }
            mx = fmaxf(mx, __shfl_xor(mx, 32, 64));
            float s = 0.f, pv[16];
            #pragma unroll
            for (int rg = 0; rg < 16; ++rg) {
                pv[rg] = (lv[rg] > -1e29f) ? __expf(lv[rg] - mx) : 0.f;
                s += pv[rg];
            }
            s += __shfl_xor(s, 32, 64);
            const float inv = 1.f / s;
            #pragma unroll
            for (int q = 0; q < 4; ++q)
                #pragma unroll
                for (int r2 = 0; r2 < 4; ++r2) {
                    int j = r2 + 8 * q + 4 * hi;
                    if (j < NEXP) {
                        float g  = pv[q * 4 + r2] * inv;
                        float eo = expl[m * NEXP + j];
                        size_t o = (size_t)(row0 + m) * NEXP + j;
                        out[o] = g * eo;                        // output
                        out[(size_t)BTOT * NEXP + o] = g;       // gate_scores
                        out[(size_t)2 * BTOT * NEXP + o] = eo;  // expert_outputs
                    }
                }
        }
    }
}

extern "C" void kernel_launch(void* const* d_in, const int* in_sizes, int n_in,
                              void* d_out, int out_size, void* d_ws, size_t ws_size,
                              hipStream_t stream) {
    (void)in_sizes; (void)n_in; (void)out_size; (void)ws_size;
    const float* x   = (const float*)d_in[0];
    const float* W1  = (const float*)d_in[1];
    const float* b1  = (const float*)d_in[2];
    const float* W2  = (const float*)d_in[3];
    const float* b2  = (const float*)d_in[4];
    const float* W3  = (const float*)d_in[5];
    const float* b3  = (const float*)d_in[6];
    const float* Wg1 = (const float*)d_in[7];
    const float* bg1 = (const float*)d_in[8];
    const float* Wg2 = (const float*)d_in[9];
    const float* bg2 = (const float*)d_in[10];

    // ws (bf16): w1t 11*25*8192 elems (4.5 MB) | w2t 20480*8 | wg2t 1024*8
    __bf16* w1t  = (__bf16*)d_ws;
    __bf16* w2t  = w1t + (size_t)11 * 25 * 8192;
    __bf16* wg2t = w2t + (size_t)20480 * 8;

    hipFuncSetAttribute((const void*)moe_fused,
                        hipFuncAttributeMaxDynamicSharedMemorySize, LDS_TOTAL);

    prep_w1<<<1100, 256, 0, stream>>>(W1, b1, Wg1, bg1, w1t);
    prep_w2<<<80, 256, 0, stream>>>(W2, w2t);
    prep_wg2<<<4, 256, 0, stream>>>(Wg2, wg2t);
    moe_fused<<<BTOT / BM, 512, LDS_TOTAL, stream>>>(x, b2, W3, b3, bg2,
                                                     w1t, w2t, wg2t, (float*)d_out);
}

// Round 12
// 436.685 us; speedup vs baseline: 1.2196x; 1.2196x over previous
//
#include <hip/hip_runtime.h>
#include <hip/hip_bf16.h>
#include <stdint.h>

// ---------------- problem dims ----------------
#define BTOT   65536
#define DIN    784
#define NH1    256
#define NH2    64
#define NEXP   10
#define BM     256
#define NKS1   25      // K1 = 800 (784 + bias row @784 + zeros), 25 steps of 32

// ---------------- LDS layout (bytes) ----------------
#define XBUF(b)   (lds + (b) * 32768)
#define WBUF(b)   (lds + (b) * 32768 + 16384)
#define H_OFF     65536                    // h-half: [mtile8][ks2l4][kh2][lane64][8] = 64K
#define EXPL_OFF  131072                   // [256 m][10 e] f32 = 10240
#define B2S_OFF   141312                   // [10][64] f32 = 2560
#define W3S_OFF   143872                   // [10][64] f32 = 2560
#define B3S_OFF   146432                   // 64
#define BG2S_OFF  146496                   // 64
#define LDS_TOTAL 146560

typedef short s16x8  __attribute__((ext_vector_type(8)));
typedef float f32x4  __attribute__((ext_vector_type(4)));
typedef float f32x16 __attribute__((ext_vector_type(16)));

__device__ __forceinline__ short bf16b(float v) {
    __bf16 b = (__bf16)v;
    return __builtin_bit_cast(short, b);
}

__device__ __forceinline__ void g2l16(const void* g, void* l) {
    __builtin_amdgcn_global_load_lds(
        (const __attribute__((address_space(1))) unsigned char*)g,
        (__attribute__((address_space(3))) unsigned char*)l, 16, 0, 0);
}

// ---------------- prep: fragment-order weights (bf16, b1 folded) ------------
// w1t [e11][ks25][nb8][kh2][lane64][8]: n=nb*32+(lane&31),
// k=ks*32+kh*16+(lane>>5)*8+j; k==784 -> bias; e==10 -> gate Wg1/bg1.
__global__ void prep_w1(const float* __restrict__ W1, const float* __restrict__ b1,
                        const float* __restrict__ Wg1, const float* __restrict__ bg1,
                        __bf16* __restrict__ dst) {
    int t = blockIdx.x * 256 + threadIdx.x;          // < 281600
    int lane = t & 63;
    int kh = (t >> 6) & 1;
    int nb = (t >> 7) & 7;
    int r  = t >> 10;
    int ks = r % 25, e = r / 25;
    int n  = nb * 32 + (lane & 31);
    int k0 = ks * 32 + kh * 16 + (lane >> 5) * 8;
    const float* src  = (e < NEXP) ? (W1 + (size_t)e * DIN * NH1) : Wg1;
    const float* bias = (e < NEXP) ? (b1 + e * NH1) : bg1;
    s16x8 o;
    #pragma unroll
    for (int j = 0; j < 8; ++j) {
        int k = k0 + j;
        float v = (k < DIN) ? src[(size_t)k * NH1 + n]
                            : ((k == DIN) ? bias[n] : 0.f);
        o[j] = bf16b(v);
    }
    *(s16x8*)((short*)dst + (size_t)t * 8) = o;
}

// w2t [e10][jb2][ks8][kh2][lane64][8]: n=jb*32+(lane&31), K2=256.
__global__ void prep_w2(const float* __restrict__ W2, __bf16* __restrict__ dst) {
    int t = blockIdx.x * 256 + threadIdx.x;          // < 20480
    int lane = t & 63;
    int kh = (t >> 6) & 1;
    int ks = (t >> 7) & 7;
    int jb = (t >> 10) & 1;
    int e  = t >> 11;
    int n  = jb * 32 + (lane & 31);
    int k0 = ks * 32 + kh * 16 + (lane >> 5) * 8;
    s16x8 o;
    #pragma unroll
    for (int j = 0; j < 8; ++j)
        o[j] = bf16b(W2[((size_t)e * NH1 + k0 + j) * NH2 + n]);
    *(s16x8*)((short*)dst + (size_t)t * 8) = o;
}

// wg2t [ks8][kh2][lane64][8]: col = lane&31 (valid <10), K2=256.
__global__ void prep_wg2(const float* __restrict__ Wg2, __bf16* __restrict__ dst) {
    int t = blockIdx.x * 256 + threadIdx.x;
    if (t >= 1024) return;
    int lane = t & 63;
    int kh = (t >> 6) & 1;
    int ks = t >> 7;
    int n  = lane & 31;
    int k0 = ks * 32 + kh * 16 + (lane >> 5) * 8;
    s16x8 o;
    #pragma unroll
    for (int j = 0; j < 8; ++j)
        o[j] = bf16b((n < NEXP) ? Wg2[(size_t)(k0 + j) * NEXP + n] : 0.f);
    *(s16x8*)((short*)dst + (size_t)t * 8) = o;
}

// prep_x: x fp32 -> bf16 fragment-order [rb256][ks25][mq8][kh2][hw2][row32][j8]
// (16 KB per (rb,ks) slice, byte-identical to the XBUF staging layout).
// Block handles 32 rows (one (rb,mq)): coalesced fp32 reads -> LDS -> 512B-run writes.
__global__ void prep_x(const float* __restrict__ x, __bf16* __restrict__ dst) {
    __shared__ short xl[32 * 800];
    const int rb = blockIdx.x >> 3, mq = blockIdx.x & 7;
    const int tid = threadIdx.x;
    const float* xg = x + ((size_t)rb * 256 + mq * 32) * DIN;
    #pragma unroll 4
    for (int i = 0; i < 25; ++i) {                   // 32*196 = 6272 float4
        int idx = tid + i * 256;
        if (idx < 6272) {
            int r = idx / 196, c = (idx % 196) * 4;
            float4 v = *(const float4*)(xg + (size_t)r * DIN + c);
            uint2 w; short* p = (short*)&w;
            p[0] = bf16b(v.x); p[1] = bf16b(v.y);
            p[2] = bf16b(v.z); p[3] = bf16b(v.w);
            *(uint2*)(xl + r * 800 + c) = w;
        }
    }
    for (int i = tid; i < 32 * 16; i += 256) {       // k=784 bias-1, 785..799 zeros
        int r = i >> 4, k = DIN + (i & 15);
        xl[r * 800 + k] = (k == DIN) ? bf16b(1.f) : (short)0;
    }
    __syncthreads();
    #pragma unroll 2
    for (int i = 0; i < 13; ++i) {                   // 3200 x 16B chunks
        int idx = tid + i * 256;
        if (idx < 3200) {
            int row = idx & 31, c8 = idx >> 5;       // c8 in [0,100)
            int ks = c8 >> 2, rem = c8 & 3;
            int kh = rem >> 1, hw = rem & 1;
            s16x8 v = *(const s16x8*)(xl + row * 800 + ks * 32 + kh * 16 + hw * 8);
            *(s16x8*)((char*)dst + (((size_t)(rb * 25 + ks) * 8 + mq) * 2048)
                      + kh * 1024 + hw * 512 + row * 16) = v;
        }
    }
}

// ---------------- fused MoE kernel ----------------
// 256 blocks x 512 thr (8 waves, 1 block/CU, 2 waves/SIMD). Per expert:
// 256x256 layer-1, K-step 32, 2-phase LDS dbuf. XWS=1: x AND W staged via
// global_load_lds from fragment-order ws (x bf16 pre-converted, L3-resident).
// XWS=0 fallback (small ws): x reg-staged fp32->bf16 per step (r11 path).
// mfma(W, x): D[n][m], m = lane&31, n = (r&3)+8*(r>>2)+4*(lane>>5).
template<int XWS>
__global__ void __launch_bounds__(512, 1)
moe_fused(const float* __restrict__ x, const __bf16* __restrict__ xt,
          const float* __restrict__ b2g, const float* __restrict__ W3,
          const float* __restrict__ b3, const float* __restrict__ bg2,
          const __bf16* __restrict__ w1t, const __bf16* __restrict__ w2t,
          const __bf16* __restrict__ wg2t, float* __restrict__ out)
{
    extern __shared__ char lds[];
    char*  hb   = lds + H_OFF;
    float* expl = (float*)(lds + EXPL_OFF);
    float* b2s  = (float*)(lds + B2S_OFF);
    float* w3s  = (float*)(lds + W3S_OFF);
    float* b3s  = (float*)(lds + B3S_OFF);
    float* bg2s = (float*)(lds + BG2S_OFF);

    const int tid  = threadIdx.x;
    const int lane = tid & 63;
    const int wave = tid >> 6;             // 0..7
    const int rl   = lane & 31;
    const int hi   = lane >> 5;
    const int mw   = wave >> 1;            // 0..3 (64-row slice)
    const int nw   = wave & 1;             // 0..1 (128-col half)
    const int row0 = blockIdx.x * BM;
    const char* w1c = (const char*)w1t;
    const char* w2c = (const char*)w2t;
    const char* wgc = (const char*)wg2t;
    const char* xtc = (const char*)xt + ((size_t)blockIdx.x * 25 << 14);

    for (int i = tid; i < NEXP * NH2; i += 512) { b2s[i] = b2g[i]; w3s[i] = W3[i]; }
    if (tid < NEXP) { b3s[tid] = b3[tid]; bg2s[tid] = bg2[tid]; }

    // ---- fallback (XWS=0) x staging state ----
    const int xrow = tid >> 1, xkh = tid & 1;
    const float* xrp = x + (size_t)(row0 + xrow) * DIN + xkh * 16;
    const int xoff = ((xrow >> 5) * 2 + xkh) * 1024 + (xrow & 31) * 16;
    float xf[16];

    #define XLOAD(KS) { if ((KS) < 24 || xkh == 0) {                          \
            _Pragma("unroll") for (int i4 = 0; i4 < 4; ++i4)                  \
                *(float4*)(xf + 4 * i4) =                                     \
                    *(const float4*)(xrp + (KS) * 32 + 4 * i4);               \
        } else { _Pragma("unroll") for (int i4 = 0; i4 < 16; ++i4)            \
                     xf[i4] = 0.f;                                            \
                 xf[0] = 1.f; } }

    #define XWRITE(B) { s16x8 l8, h8;                                         \
            _Pragma("unroll") for (int j = 0; j < 8; ++j) {                   \
                l8[j] = bf16b(xf[j]); h8[j] = bf16b(xf[8 + j]); }             \
            *(s16x8*)(XBUF(B) + xoff)       = l8;                             \
            *(s16x8*)(XBUF(B) + xoff + 512) = h8; }

    #define WSTAGE(B, E, KS) {                                                \
            const char* ws_ = w1c + (((size_t)(E) * 25 + (KS)) << 14)         \
                              + tid * 16;                                     \
            char* wd_ = WBUF(B) + tid * 16;                                   \
            g2l16(ws_, wd_); g2l16(ws_ + 8192, wd_ + 8192); }

    #define XSTAGE(B, KS) {                                                   \
            const char* xs_ = xtc + ((size_t)(KS) << 14) + tid * 16;          \
            char* xd_ = XBUF(B) + tid * 16;                                   \
            g2l16(xs_, xd_); g2l16(xs_ + 8192, xd_ + 8192); }

    f32x16 acc[4][2];                      // [nt][mt]
    f32x16 acc2[2];                        // layer-2 per jb (gate uses [0])

    #pragma unroll 1
    for (int e = 0; e <= NEXP; ++e) {
        // ---- stage ks=0 into buf0 ----
        if constexpr (XWS) {
            XSTAGE(0, 0)
            WSTAGE(0, e, 0)
        } else {
            XLOAD(0)
            WSTAGE(0, e, 0)
            XWRITE(0)
        }
        __syncthreads();

        #pragma unroll
        for (int nt = 0; nt < 4; ++nt)
            #pragma unroll
            for (int mt = 0; mt < 2; ++mt)
                #pragma unroll
                for (int q = 0; q < 16; ++q) acc[nt][mt][q] = 0.f;
        #pragma unroll
        for (int q = 0; q < 16; ++q) { acc2[0][q] = 0.f; acc2[1][q] = 0.f; }

        // ---- K loop: 2-phase dbuf, stage(next) issued before compute(cur) ----
        int cur = 0;
        #pragma unroll 1
        for (int ks = 0; ks < NKS1; ++ks) {
            if constexpr (XWS) {
                if (ks < 24) {
                    XSTAGE(cur ^ 1, ks + 1)
                    WSTAGE(cur ^ 1, e, ks + 1)
                }
            } else {
                if (ks < 24) {
                    XLOAD(ks + 1)
                    WSTAGE(cur ^ 1, e, ks + 1)
                }
            }
            const char* ab = XBUF(cur) + mw * 4096 + lane * 16;
            const char* wb = WBUF(cur) + nw * 8192 + lane * 16;
            s16x8 xv[2][2], wv[4][2];
            #pragma unroll
            for (int mt = 0; mt < 2; ++mt)
                #pragma unroll
                for (int kh = 0; kh < 2; ++kh)
                    xv[mt][kh] = *(const s16x8*)(ab + (mt * 2 + kh) * 1024);
            #pragma unroll
            for (int nt = 0; nt < 4; ++nt)
                #pragma unroll
                for (int kh = 0; kh < 2; ++kh)
                    wv[nt][kh] = *(const s16x8*)(wb + (nt * 2 + kh) * 1024);
            #pragma unroll
            for (int kh = 0; kh < 2; ++kh)
                #pragma unroll
                for (int nt = 0; nt < 4; ++nt)
                    #pragma unroll
                    for (int mt = 0; mt < 2; ++mt)
                        acc[nt][mt] = __builtin_amdgcn_mfma_f32_32x32x16_bf16(
                            wv[nt][kh], xv[mt][kh], acc[nt][mt], 0, 0, 0);
            if constexpr (!XWS) { if (ks < 24) XWRITE(cur ^ 1) }
            __syncthreads();               // 2-phase drain (covered by 256cyc MFMA)
            cur ^= 1;
        }

        // ---- epilogue: h in two 128-col halves through 64 KB LDS ----
        #pragma unroll
        for (int half = 0; half < 2; ++half) {
            if (nw == half) {
                #pragma unroll
                for (int mt = 0; mt < 2; ++mt)
                    #pragma unroll
                    for (int nt = 0; nt < 4; ++nt)
                        #pragma unroll
                        for (int q = 0; q < 4; ++q) {
                            uint2 wvv; short* p = (short*)&wvv;
                            #pragma unroll
                            for (int r2 = 0; r2 < 4; ++r2)
                                p[r2] = bf16b(fmaxf(acc[nt][mt][q * 4 + r2], 0.f));
                            *(uint2*)(hb + (((mw * 2 + mt) * 4 + nt) * 2 + (q >> 1)) * 1024
                                         + (rl + 32 * (q & 1)) * 16 + hi * 8) = wvv;
                        }
            }
            __syncthreads();               // h-half ready
            if (e < NEXP) {
                #pragma unroll
                for (int jb = 0; jb < 2; ++jb)
                    #pragma unroll
                    for (int k2 = 0; k2 < 4; ++k2)
                        #pragma unroll
                        for (int kh = 0; kh < 2; ++kh) {
                            s16x8 hf = *(const s16x8*)(hb + ((wave * 4 + k2) * 2 + kh) * 1024
                                                       + lane * 16);
                            s16x8 wf = *(const s16x8*)(w2c
                                + ((((size_t)e * 2 + jb) * 8 + half * 4 + k2) * 2 + kh) * 1024
                                + lane * 16);
                            acc2[jb] = __builtin_amdgcn_mfma_f32_32x32x16_bf16(
                                wf, hf, acc2[jb], 0, 0, 0);
                        }
            } else {
                #pragma unroll
                for (int k2 = 0; k2 < 4; ++k2)
                    #pragma unroll
                    for (int kh = 0; kh < 2; ++kh) {
                        s16x8 hf = *(const s16x8*)(hb + ((wave * 4 + k2) * 2 + kh) * 1024
                                                   + lane * 16);
                        s16x8 gf = *(const s16x8*)(wgc
                            + ((half * 4 + k2) * 2 + kh) * 1024 + lane * 16);
                        acc2[0] = __builtin_amdgcn_mfma_f32_32x32x16_bf16(
                            gf, hf, acc2[0], 0, 0, 0);
                    }
            }
            __syncthreads();               // reads done before next half overwrite
        }

        if (e < NEXP) {
            // ---- layer 3: lane m = wave*32+rl ----
            float part = 0.f;
            #pragma unroll
            for (int jb = 0; jb < 2; ++jb)
                #pragma unroll
                for (int q = 0; q < 4; ++q) {
                    f32x4 b2v = *(const f32x4*)(b2s + e * NH2 + jb * 32 + 8 * q + 4 * hi);
                    f32x4 w3v = *(const f32x4*)(w3s + e * NH2 + jb * 32 + 8 * q + 4 * hi);
                    #pragma unroll
                    for (int r2 = 0; r2 < 4; ++r2)
                        part += fmaxf(acc2[jb][q * 4 + r2] + b2v[r2], 0.f) * w3v[r2];
                }
            part += __shfl_xor(part, 32, 64);
            if (hi == 0)
                expl[(wave * 32 + rl) * NEXP + e] = part + b3s[e];
        } else {
            // ---- gate softmax + combine: lane m = wave*32+rl, j = r2+8q+4hi ----
            const int m = wave * 32 + rl;
            float lv[16], mx = -1e30f;
            #pragma unroll
            for (int q = 0; q < 4; ++q)
                #pragma unroll
                for (int r2 = 0; r2 < 4; ++r2) {
                    int j = r2 + 8 * q + 4 * hi;
                    int rg = q * 4 + r2;
                    lv[rg] = (j < NEXP) ? (acc2[0][rg] + bg2s[j]) : -1e30f;
                    mx = fmaxf(mx, lv[rg]);
                }
            mx = fmaxf(mx, __shfl_xor(mx, 32, 64));
            float s = 0.f, pv[16];
            #pragma unroll
            for (int rg = 0; rg < 16; ++rg) {
                pv[rg] = (lv[rg] > -1e29f) ? __expf(lv[rg] - mx) : 0.f;
                s += pv[rg];
            }
            s += __shfl_xor(s, 32, 64);
            const float inv = 1.f / s;
            #pragma unroll
            for (int q = 0; q < 4; ++q)
                #pragma unroll
                for (int r2 = 0; r2 < 4; ++r2) {
                    int j = r2 + 8 * q + 4 * hi;
                    if (j < NEXP) {
                        float g  = pv[q * 4 + r2] * inv;
                        float eo = expl[m * NEXP + j];
                        size_t o = (size_t)(row0 + m) * NEXP + j;
                        out[o] = g * eo;                        // output
                        out[(size_t)BTOT * NEXP + o] = g;       // gate_scores
                        out[(size_t)2 * BTOT * NEXP + o] = eo;  // expert_outputs
                    }
                }
        }
    }
    #undef XLOAD
    #undef XWRITE
    #undef WSTAGE
    #undef XSTAGE
}

extern "C" void kernel_launch(void* const* d_in, const int* in_sizes, int n_in,
                              void* d_out, int out_size, void* d_ws, size_t ws_size,
                              hipStream_t stream) {
    (void)in_sizes; (void)n_in; (void)out_size;
    const float* x   = (const float*)d_in[0];
    const float* W1  = (const float*)d_in[1];
    const float* b1  = (const float*)d_in[2];
    const float* W2  = (const float*)d_in[3];
    const float* b2  = (const float*)d_in[4];
    const float* W3  = (const float*)d_in[5];
    const float* b3  = (const float*)d_in[6];
    const float* Wg1 = (const float*)d_in[7];
    const float* bg1 = (const float*)d_in[8];
    const float* Wg2 = (const float*)d_in[9];
    const float* bg2 = (const float*)d_in[10];

    // ws layout (bf16): w1t 11*25*8192 | w2t 20480*8 | wg2t 1024*8 | xt [256][25][8192]
    __bf16* w1t  = (__bf16*)d_ws;
    __bf16* w2t  = w1t + (size_t)11 * 25 * 8192;
    __bf16* wg2t = w2t + (size_t)20480 * 8;
    __bf16* xt   = wg2t + (size_t)1024 * 8;
    size_t need  = ((char*)(xt + (size_t)256 * 25 * 8192) - (char*)d_ws);
    const bool xws = ws_size >= need;

    hipFuncSetAttribute((const void*)moe_fused<1>,
                        hipFuncAttributeMaxDynamicSharedMemorySize, LDS_TOTAL);
    hipFuncSetAttribute((const void*)moe_fused<0>,
                        hipFuncAttributeMaxDynamicSharedMemorySize, LDS_TOTAL);

    prep_w1<<<1100, 256, 0, stream>>>(W1, b1, Wg1, bg1, w1t);
    prep_w2<<<80, 256, 0, stream>>>(W2, w2t);
    prep_wg2<<<4, 256, 0, stream>>>(Wg2, wg2t);
    if (xws) {
        prep_x<<<2048, 256, 0, stream>>>(x, xt);
        moe_fused<1><<<BTOT / BM, 512, LDS_TOTAL, stream>>>(
            x, xt, b2, W3, b3, bg2, w1t, w2t, wg2t, (float*)d_out);
    } else {
        moe_fused<0><<<BTOT / BM, 512, LDS_TOTAL, stream>>>(
            x, xt, b2, W3, b3, bg2, w1t, w2t, wg2t, (float*)d_out);
    }
}

// Round 13
// 398.379 us; speedup vs baseline: 1.3369x; 1.0962x over previous
//
#include <hip/hip_runtime.h>
#include <hip/hip_bf16.h>
#include <stdint.h>

// ---------------- problem dims ----------------
#define BTOT   65536
#define DIN    784
#define NH1    256
#define NH2    64
#define NEXP   10
#define BM     256
#define NKS1   25      // K1 = 800 (784 + bias row @784 + zeros), 25 steps of 32

// ---------------- LDS layout (bytes) ----------------
// 3-slot staging ring, 32 KB each: slot s = lds + s*32768 (x 16K | w 16K).
// h (64 KB) OVERLAYS slots 0-1 (used only after the K-loop fully drains).
#define SLOT(s)   (lds + (s) * 32768)
#define EXPL_OFF  98304                    // [256 m][10 e] f32 = 10240
#define B2S_OFF   108544                   // [10][64] f32 = 2560
#define W3S_OFF   111104                   // [10][64] f32 = 2560
#define B3S_OFF   113664                   // 64
#define BG2S_OFF  113728                   // 64
#define LDS_TOTAL 113792

typedef short s16x8  __attribute__((ext_vector_type(8)));
typedef float f32x4  __attribute__((ext_vector_type(4)));
typedef float f32x16 __attribute__((ext_vector_type(16)));

__device__ __forceinline__ short bf16b(float v) {
    __bf16 b = (__bf16)v;
    return __builtin_bit_cast(short, b);
}

__device__ __forceinline__ void g2l16(const void* g, void* l) {
    __builtin_amdgcn_global_load_lds(
        (const __attribute__((address_space(1))) unsigned char*)g,
        (__attribute__((address_space(3))) unsigned char*)l, 16, 0, 0);
}

// ---------------- prep: fragment-order weights (bf16, b1 folded) ------------
// w1t [e11][ks25][nb8][kh2][lane64][8]: n=nb*32+(lane&31),
// k=ks*32+kh*16+(lane>>5)*8+j; k==784 -> bias; e==10 -> gate Wg1/bg1.
__global__ void prep_w1(const float* __restrict__ W1, const float* __restrict__ b1,
                        const float* __restrict__ Wg1, const float* __restrict__ bg1,
                        __bf16* __restrict__ dst) {
    int t = blockIdx.x * 256 + threadIdx.x;          // < 281600
    int lane = t & 63;
    int kh = (t >> 6) & 1;
    int nb = (t >> 7) & 7;
    int r  = t >> 10;
    int ks = r % 25, e = r / 25;
    int n  = nb * 32 + (lane & 31);
    int k0 = ks * 32 + kh * 16 + (lane >> 5) * 8;
    const float* src  = (e < NEXP) ? (W1 + (size_t)e * DIN * NH1) : Wg1;
    const float* bias = (e < NEXP) ? (b1 + e * NH1) : bg1;
    s16x8 o;
    #pragma unroll
    for (int j = 0; j < 8; ++j) {
        int k = k0 + j;
        float v = (k < DIN) ? src[(size_t)k * NH1 + n]
                            : ((k == DIN) ? bias[n] : 0.f);
        o[j] = bf16b(v);
    }
    *(s16x8*)((short*)dst + (size_t)t * 8) = o;
}

// w2t [e10][jb2][ks8][kh2][lane64][8]: n=jb*32+(lane&31), K2=256.
__global__ void prep_w2(const float* __restrict__ W2, __bf16* __restrict__ dst) {
    int t = blockIdx.x * 256 + threadIdx.x;          // < 20480
    int lane = t & 63;
    int kh = (t >> 6) & 1;
    int ks = (t >> 7) & 7;
    int jb = (t >> 10) & 1;
    int e  = t >> 11;
    int n  = jb * 32 + (lane & 31);
    int k0 = ks * 32 + kh * 16 + (lane >> 5) * 8;
    s16x8 o;
    #pragma unroll
    for (int j = 0; j < 8; ++j)
        o[j] = bf16b(W2[((size_t)e * NH1 + k0 + j) * NH2 + n]);
    *(s16x8*)((short*)dst + (size_t)t * 8) = o;
}

// wg2t [ks8][kh2][lane64][8]: col = lane&31 (valid <10), K2=256.
__global__ void prep_wg2(const float* __restrict__ Wg2, __bf16* __restrict__ dst) {
    int t = blockIdx.x * 256 + threadIdx.x;
    if (t >= 1024) return;
    int lane = t & 63;
    int kh = (t >> 6) & 1;
    int ks = t >> 7;
    int n  = lane & 31;
    int k0 = ks * 32 + kh * 16 + (lane >> 5) * 8;
    s16x8 o;
    #pragma unroll
    for (int j = 0; j < 8; ++j)
        o[j] = bf16b((n < NEXP) ? Wg2[(size_t)(k0 + j) * NEXP + n] : 0.f);
    *(s16x8*)((short*)dst + (size_t)t * 8) = o;
}

// prep_x: x fp32 -> bf16 fragment-order [rb256][ks25][mq8][kh2][hw2][row32][j8]
__global__ void prep_x(const float* __restrict__ x, __bf16* __restrict__ dst) {
    __shared__ short xl[32 * 800];
    const int rb = blockIdx.x >> 3, mq = blockIdx.x & 7;
    const int tid = threadIdx.x;
    const float* xg = x + ((size_t)rb * 256 + mq * 32) * DIN;
    #pragma unroll 4
    for (int i = 0; i < 25; ++i) {                   // 32*196 = 6272 float4
        int idx = tid + i * 256;
        if (idx < 6272) {
            int r = idx / 196, c = (idx % 196) * 4;
            float4 v = *(const float4*)(xg + (size_t)r * DIN + c);
            uint2 w; short* p = (short*)&w;
            p[0] = bf16b(v.x); p[1] = bf16b(v.y);
            p[2] = bf16b(v.z); p[3] = bf16b(v.w);
            *(uint2*)(xl + r * 800 + c) = w;
        }
    }
    for (int i = tid; i < 32 * 16; i += 256) {       // k=784 bias-1, 785..799 zeros
        int r = i >> 4, k = DIN + (i & 15);
        xl[r * 800 + k] = (k == DIN) ? bf16b(1.f) : (short)0;
    }
    __syncthreads();
    #pragma unroll 2
    for (int i = 0; i < 13; ++i) {                   // 3200 x 16B chunks
        int idx = tid + i * 256;
        if (idx < 3200) {
            int row = idx & 31, c8 = idx >> 5;       // c8 in [0,100)
            int ks = c8 >> 2, rem = c8 & 3;
            int kh = rem >> 1, hw = rem & 1;
            s16x8 v = *(const s16x8*)(xl + row * 800 + ks * 32 + kh * 16 + hw * 8);
            *(s16x8*)((char*)dst + (((size_t)(rb * 25 + ks) * 8 + mq) * 2048)
                      + kh * 1024 + hw * 512 + row * 16) = v;
        }
    }
}

// ---- staging + body macros ----
#define STAGE(S, E, KS) {                                                     \
        const char* xs_ = xtc + ((size_t)(KS) << 14) + tid * 16;              \
        char* xd_ = SLOT(S) + tid * 16;                                       \
        g2l16(xs_, xd_); g2l16(xs_ + 8192, xd_ + 8192);                       \
        const char* ws_ = w1c + (((size_t)(E) * 25 + (KS)) << 14) + tid * 16; \
        char* wd_ = SLOT(S) + 16384 + tid * 16;                               \
        g2l16(ws_, wd_); g2l16(ws_ + 8192, wd_ + 8192); }

#define COMPUTE(S) {                                                          \
        const char* ab = SLOT(S) + mw * 4096 + lane * 16;                     \
        const char* wb = SLOT(S) + 16384 + nw * 8192 + lane * 16;             \
        s16x8 xv[2][2], wv[4][2];                                             \
        _Pragma("unroll") for (int mt = 0; mt < 2; ++mt)                      \
            _Pragma("unroll") for (int kh = 0; kh < 2; ++kh)                  \
                xv[mt][kh] = *(const s16x8*)(ab + (mt * 2 + kh) * 1024);      \
        _Pragma("unroll") for (int nt = 0; nt < 4; ++nt)                      \
            _Pragma("unroll") for (int kh = 0; kh < 2; ++kh)                  \
                wv[nt][kh] = *(const s16x8*)(wb + (nt * 2 + kh) * 1024);      \
        _Pragma("unroll") for (int kh = 0; kh < 2; ++kh)                      \
            _Pragma("unroll") for (int nt = 0; nt < 4; ++nt)                  \
                _Pragma("unroll") for (int mt = 0; mt < 2; ++mt)              \
                    acc[nt][mt] = __builtin_amdgcn_mfma_f32_32x32x16_bf16(    \
                        wv[nt][kh], xv[mt][kh], acc[nt][mt], 0, 0, 0); }

// counted-vmcnt sync: wait own stage (oldest 4 of 8 in flight), barrier, fence
#define RING_SYNC(VN) {                                                       \
        asm volatile("s_waitcnt vmcnt(" #VN ")" ::: "memory");                \
        __builtin_amdgcn_s_barrier();                                         \
        asm volatile("" ::: "memory"); }

#define BODY(S, KS) {                                                         \
        RING_SYNC(4)                                                          \
        COMPUTE(S)                                                            \
        if ((KS) + 2 <= 24) STAGE(((S) + 2) % 3, e, (KS) + 2) }

// ---------------- fused MoE kernel ----------------
// 256 blocks x 512 thr (8 waves, 1 block/CU, 2 waves/SIMD). Per expert:
// 256x256 layer-1 GEMM, K-step 32, 3-slot LDS ring, depth-2 prefetch with
// COUNTED vmcnt (never 0 in the loop) -> HBM/L3 miss latency spans ~2 steps.
// x and W both staged via global_load_lds from fragment-order ws.
// mfma(W, x): D[n][m], m = lane&31, n = (r&3)+8*(r>>2)+4*(lane>>5).
__global__ void __launch_bounds__(512, 1)
moe_fused(const __bf16* __restrict__ xt, const float* __restrict__ b2g,
          const float* __restrict__ W3, const float* __restrict__ b3,
          const float* __restrict__ bg2, const __bf16* __restrict__ w1t,
          const __bf16* __restrict__ w2t, const __bf16* __restrict__ wg2t,
          float* __restrict__ out)
{
    extern __shared__ char lds[];
    char*  hb   = lds;                     // overlays slots 0-1 (epilogue only)
    float* expl = (float*)(lds + EXPL_OFF);
    float* b2s  = (float*)(lds + B2S_OFF);
    float* w3s  = (float*)(lds + W3S_OFF);
    float* b3s  = (float*)(lds + B3S_OFF);
    float* bg2s = (float*)(lds + BG2S_OFF);

    const int tid  = threadIdx.x;
    const int lane = tid & 63;
    const int wave = tid >> 6;             // 0..7
    const int rl   = lane & 31;
    const int hi   = lane >> 5;
    const int mw   = wave >> 1;            // 0..3 (64-row slice)
    const int nw   = wave & 1;             // 0..1 (128-col half)
    const int row0 = blockIdx.x * BM;
    const char* w1c = (const char*)w1t;
    const char* w2c = (const char*)w2t;
    const char* wgc = (const char*)wg2t;
    const char* xtc = (const char*)xt + ((size_t)blockIdx.x * 25 << 14);

    for (int i = tid; i < NEXP * NH2; i += 512) { b2s[i] = b2g[i]; w3s[i] = W3[i]; }
    if (tid < NEXP) { b3s[tid] = b3[tid]; bg2s[tid] = bg2[tid]; }
    __syncthreads();                       // drain: vmcnt known-0 entering loop

    f32x16 acc[4][2];                      // [nt][mt]
    f32x16 acc2[2];                        // layer-2 per jb (gate uses [0])

    #pragma unroll 1
    for (int e = 0; e <= NEXP; ++e) {
        #pragma unroll
        for (int nt = 0; nt < 4; ++nt)
            #pragma unroll
            for (int mt = 0; mt < 2; ++mt)
                #pragma unroll
                for (int q = 0; q < 16; ++q) acc[nt][mt][q] = 0.f;
        #pragma unroll
        for (int q = 0; q < 16; ++q) { acc2[0][q] = 0.f; acc2[1][q] = 0.f; }

        // ---- prologue: stage ks=0,1 (8 loads/thread in flight) ----
        STAGE(0, e, 0)
        STAGE(1, e, 1)

        // ---- K loop: 24 steps via 8 x 3 static slot-bodies ----
        #pragma unroll 1
        for (int T = 0; T < 8; ++T) {
            const int t3 = 3 * T;
            BODY(0, t3)
            BODY(1, t3 + 1)
            BODY(2, t3 + 2)
        }
        // peeled ks=24 (slot 0): drain its stage fully
        RING_SYNC(0)
        COMPUTE(0)
        __syncthreads();                   // all reads of ring done; h may overlay

        // ---- epilogue: h in two 128-col halves through overlay buffer ----
        #pragma unroll
        for (int half = 0; half < 2; ++half) {
            if (nw == half) {
                #pragma unroll
                for (int mt = 0; mt < 2; ++mt)
                    #pragma unroll
                    for (int nt = 0; nt < 4; ++nt)
                        #pragma unroll
                        for (int q = 0; q < 4; ++q) {
                            uint2 wvv; short* p = (short*)&wvv;
                            #pragma unroll
                            for (int r2 = 0; r2 < 4; ++r2)
                                p[r2] = bf16b(fmaxf(acc[nt][mt][q * 4 + r2], 0.f));
                            *(uint2*)(hb + (((mw * 2 + mt) * 4 + nt) * 2 + (q >> 1)) * 1024
                                         + (rl + 32 * (q & 1)) * 16 + hi * 8) = wvv;
                        }
            }
            __syncthreads();               // h-half ready
            if (e < NEXP) {
                #pragma unroll
                for (int jb = 0; jb < 2; ++jb)
                    #pragma unroll
                    for (int k2 = 0; k2 < 4; ++k2)
                        #pragma unroll
                        for (int kh = 0; kh < 2; ++kh) {
                            s16x8 hf = *(const s16x8*)(hb + ((wave * 4 + k2) * 2 + kh) * 1024
                                                       + lane * 16);
                            s16x8 wf = *(const s16x8*)(w2c
                                + ((((size_t)e * 2 + jb) * 8 + half * 4 + k2) * 2 + kh) * 1024
                                + lane * 16);
                            acc2[jb] = __builtin_amdgcn_mfma_f32_32x32x16_bf16(
                                wf, hf, acc2[jb], 0, 0, 0);
                        }
            } else {
                #pragma unroll
                for (int k2 = 0; k2 < 4; ++k2)
                    #pragma unroll
                    for (int kh = 0; kh < 2; ++kh) {
                        s16x8 hf = *(const s16x8*)(hb + ((wave * 4 + k2) * 2 + kh) * 1024
                                                   + lane * 16);
                        s16x8 gf = *(const s16x8*)(wgc
                            + ((half * 4 + k2) * 2 + kh) * 1024 + lane * 16);
                        acc2[0] = __builtin_amdgcn_mfma_f32_32x32x16_bf16(
                            gf, hf, acc2[0], 0, 0, 0);
                    }
            }
            __syncthreads();               // reads done before next half / prologue
        }

        if (e < NEXP) {
            // ---- layer 3: lane m = wave*32+rl ----
            float part = 0.f;
            #pragma unroll
            for (int jb = 0; jb < 2; ++jb)
                #pragma unroll
                for (int q = 0; q < 4; ++q) {
                    f32x4 b2v = *(const f32x4*)(b2s + e * NH2 + jb * 32 + 8 * q + 4 * hi);
                    f32x4 w3v = *(const f32x4*)(w3s + e * NH2 + jb * 32 + 8 * q + 4 * hi);
                    #pragma unroll
                    for (int r2 = 0; r2 < 4; ++r2)
                        part += fmaxf(acc2[jb][q * 4 + r2] + b2v[r2], 0.f) * w3v[r2];
                }
            part += __shfl_xor(part, 32, 64);
            if (hi == 0)
                expl[(wave * 32 + rl) * NEXP + e] = part + b3s[e];
        } else {
            // ---- gate softmax + combine: lane m = wave*32+rl, j = r2+8q+4hi ----
            const int m = wave * 32 + rl;
            float lv[16], mx = -1e30f;
            #pragma unroll
            for (int q = 0; q < 4; ++q)
                #pragma unroll
                for (int r2 = 0; r2 < 4; ++r2) {
                    int j = r2 + 8 * q + 4 * hi;
                    int rg = q * 4 + r2;
                    lv[rg] = (j < NEXP) ? (acc2[0][rg] + bg2s[j]) : -1e30f;
                    mx = fmaxf(mx, lv[rg]);
                }
            mx = fmaxf(mx, __shfl_xor(mx, 32, 64));
            float s = 0.f, pv[16];
            #pragma unroll
            for (int rg = 0; rg < 16; ++rg) {
                pv[rg] = (lv[rg] > -1e29f) ? __expf(lv[rg] - mx) : 0.f;
                s += pv[rg];
            }
            s += __shfl_xor(s, 32, 64);
            const float inv = 1.f / s;
            #pragma unroll
            for (int q = 0; q < 4; ++q)
                #pragma unroll
                for (int r2 = 0; r2 < 4; ++r2) {
                    int j = r2 + 8 * q + 4 * hi;
                    if (j < NEXP) {
                        float g  = pv[q * 4 + r2] * inv;
                        float eo = expl[m * NEXP + j];
                        size_t o = (size_t)(row0 + m) * NEXP + j;
                        out[o] = g * eo;                        // output
                        out[(size_t)BTOT * NEXP + o] = g;       // gate_scores
                        out[(size_t)2 * BTOT * NEXP + o] = eo;  // expert_outputs
                    }
                }
        }
    }
}

extern "C" void kernel_launch(void* const* d_in, const int* in_sizes, int n_in,
                              void* d_out, int out_size, void* d_ws, size_t ws_size,
                              hipStream_t stream) {
    (void)in_sizes; (void)n_in; (void)out_size; (void)ws_size;
    const float* x   = (const float*)d_in[0];
    const float* W1  = (const float*)d_in[1];
    const float* b1  = (const float*)d_in[2];
    const float* W2  = (const float*)d_in[3];
    const float* b2  = (const float*)d_in[4];
    const float* W3  = (const float*)d_in[5];
    const float* b3  = (const float*)d_in[6];
    const float* Wg1 = (const float*)d_in[7];
    const float* bg1 = (const float*)d_in[8];
    const float* Wg2 = (const float*)d_in[9];
    const float* bg2 = (const float*)d_in[10];

    // ws layout (bf16): w1t 11*25*8192 | w2t 20480*8 | wg2t 1024*8 | xt [256][25][8192]
    // total ~110 MB (r12 verified ws_size sufficient).
    __bf16* w1t  = (__bf16*)d_ws;
    __bf16* w2t  = w1t + (size_t)11 * 25 * 8192;
    __bf16* wg2t = w2t + (size_t)20480 * 8;
    __bf16* xt   = wg2t + (size_t)1024 * 8;

    hipFuncSetAttribute((const void*)moe_fused,
                        hipFuncAttributeMaxDynamicSharedMemorySize, LDS_TOTAL);

    prep_w1<<<1100, 256, 0, stream>>>(W1, b1, Wg1, bg1, w1t);
    prep_w2<<<80, 256, 0, stream>>>(W2, w2t);
    prep_wg2<<<4, 256, 0, stream>>>(Wg2, wg2t);
    prep_x<<<2048, 256, 0, stream>>>(x, xt);
    moe_fused<<<BTOT / BM, 512, LDS_TOTAL, stream>>>(
        xt, b2, W3, b3, bg2, w1t, w2t, wg2t, (float*)d_out);
}